// Round 2
// baseline (508.050 us; speedup 1.0000x reference)
//
#include <hip/hip_runtime.h>
#include <math.h>

constexpr int kN  = 4096;
constexpr int kFI = 128;
constexpr int kFO = 64;
constexpr int kH  = 4;
constexpr int kHF = 256;   // kH*kFO
constexpr float kNegInf = -1e9f;
constexpr float kLnEps  = 1e-5f;
constexpr float kL2E    = 1.44269504f;

typedef short bf16x8 __attribute__((ext_vector_type(8)));
typedef float f32x4  __attribute__((ext_vector_type(4)));

__device__ __forceinline__ float lrelu(float x){ return x >= 0.f ? x : 0.2f*x; }

__device__ __forceinline__ float wave_sum(float v){
  #pragma unroll
  for (int s = 32; s > 0; s >>= 1) v += __shfl_xor(v, s, 64);
  return v;
}

__device__ __forceinline__ unsigned short f2bf(float x){
  unsigned u = __float_as_uint(x);
  u = (u + 0x7fffu + ((u >> 16) & 1u)) >> 16;
  return (unsigned short)u;
}
__device__ __forceinline__ unsigned f2bf_pk(float a, float b){
  return (unsigned)f2bf(a) | ((unsigned)f2bf(b) << 16);
}

// ---------------------------------------------------------------------------
// K0: transpose skw [256][128] -> skwT [128][256] so k_proj reads coalesce.
// ---------------------------------------------------------------------------
__global__ __launch_bounds__(256) void k_tr(
    const float* __restrict__ skw, float* __restrict__ skwT)
{
  const int k  = blockIdx.x;      // 0..127
  const int hf = threadIdx.x;     // 0..255
  skwT[k*kHF + hf] = skw[hf*kFI + k];
}

// ---------------------------------------------------------------------------
// K1: proj[h][n][o], ga/gb scores, skip = nodes @ skw^T. 8 nodes/block,
// 512 blocks. 2-stage register prefetch of the p/w batches across the
// k-loop so L2 latency hides under the FMA chains.
// ---------------------------------------------------------------------------
__global__ __launch_bounds__(256) void k_proj(
    const float* __restrict__ nodes, const float* __restrict__ pp,
    const float* __restrict__ ssrc,  const float* __restrict__ stgt,
    const float* __restrict__ skwT,
    float* __restrict__ proj, float* __restrict__ ga, float* __restrict__ gb,
    float* __restrict__ skipo)
{
  __shared__ float feat[8][kFI];    // 4 KB
  const int tid = threadIdx.x;
  const int n0  = blockIdx.x * 8;
  for (int idx = tid; idx < 8*kFI; idx += 256)
    feat[idx >> 7][idx & 127] = nodes[n0*kFI + idx];
  __syncthreads();
  const int h = tid >> 6, o = tid & 63;
  float accP[8], accS[8];
  #pragma unroll
  for (int n = 0; n < 8; ++n){ accP[n] = 0.f; accS[n] = 0.f; }

  auto LOADK = [&](int kk, float* p, float* w){
    #pragma unroll
    for (int u = 0; u < 4; ++u){
      p[u] = pp[(h*kFI + kk+u)*kFO + o];
      w[u] = skwT[(kk+u)*kHF + tid];
    }
  };
  auto COMP = [&](int kk, const float* p, const float* w){
    #pragma unroll
    for (int n = 0; n < 8; ++n){
      const float4 f4 = *(const float4*)&feat[n][kk];
      accP[n] = fmaf(f4.x, p[0], fmaf(f4.y, p[1],
                fmaf(f4.z, p[2], fmaf(f4.w, p[3], accP[n]))));
      accS[n] = fmaf(f4.x, w[0], fmaf(f4.y, w[1],
                fmaf(f4.z, w[2], fmaf(f4.w, w[3], accS[n]))));
    }
  };

  float pA[4], wA[4], pB[4], wB[4];
  LOADK(0, pA, wA);
  #pragma unroll
  for (int k0 = 0; k0 < kFI; k0 += 8){
    LOADK(k0+4, pB, wB);
    COMP(k0, pA, wA);
    if (k0+8 < kFI) LOADK(k0+8, pA, wA);
    COMP(k0+4, pB, wB);
  }

  const float sa = ssrc[h*kFO + o];
  const float sb = stgt[h*kFO + o];
  #pragma unroll
  for (int n = 0; n < 8; ++n){
    proj[(h*kN + n0+n)*kFO + o] = accP[n];
    skipo[(n0+n)*kHF + tid]     = accS[n];
    const float va = wave_sum(accP[n] * sa);
    const float vb = wave_sum(accP[n] * sb);
    if (o == 0){ ga[h*kN + n0+n] = va; gb[h*kN + n0+n] = vb; }
  }
}

// ---------------------------------------------------------------------------
// K2: column pass + row LN stat partials. R1 post-mortem: occupancy 20->47%
// changed NOTHING -> cap is per-wave MLP (launch_bounds(,6) forced 40 VGPR,
// splitting the load batch). Now: no min-wave bound; ALL 16 float4 loads of
// an 8-row group issued up-front (64 VGPRs of data in flight per thread).
// exp2f + shared m*log2e shaves ~4 VALU/element across the 4 heads.
// ---------------------------------------------------------------------------
template<int RS>
__global__ __launch_bounds__(256) void k_colsum(
    const float* __restrict__ degm, const float* __restrict__ bondm,
    const float* __restrict__ ga,   const float* __restrict__ gb,
    const int* __restrict__ cutp,
    float* __restrict__ Spart, float* __restrict__ statg,
    float* __restrict__ maskws, int write_mask)
{
  const int j0 = (blockIdx.x * 256 + threadIdx.x) * 4;
  const int lane = threadIdx.x & 63;
  const float cut = (float)cutp[0];
  float4 bv[kH]; f32x4 sv[kH];
  #pragma unroll
  for (int h = 0; h < kH; ++h){
    bv[h] = *(const float4*)&gb[h*kN + j0];
    sv[h] = (f32x4){0.f, 0.f, 0.f, 0.f};
  }
  float msum[RS], msq[RS];
  #pragma unroll
  for (int r = 0; r < RS; ++r){ msum[r] = 0.f; msq[r] = 0.f; }

  const int i0 = blockIdx.y * RS;
  #pragma unroll
  for (int ib = 0; ib < RS; ib += 8){
    // all 16 loads of the 8-row group in flight before any consumption
    float4 dg[8], bd[8];
    #pragma unroll
    for (int u = 0; u < 8; ++u){
      const size_t off = (size_t)(i0+ib+u)*kN + j0;
      dg[u] = *(const float4*)&degm[off];
      bd[u] = *(const float4*)&bondm[off];
    }
    #pragma unroll
    for (int u = 0; u < 8; ++u){
      const int i = i0 + ib + u;
      float4 m;
      {
        float w0 = dg[u].x + bd[u].x, w1 = dg[u].y + bd[u].y;
        float w2 = dg[u].z + bd[u].z, w3 = dg[u].w + bd[u].w;
        m.x = w0 > 0.f ? w0 : (bd[u].x > cut ? bd[u].x + w0 : kNegInf);
        m.y = w1 > 0.f ? w1 : (bd[u].y > cut ? bd[u].y + w1 : kNegInf);
        m.z = w2 > 0.f ? w2 : (bd[u].z > cut ? bd[u].z + w2 : kNegInf);
        m.w = w3 > 0.f ? w3 : (bd[u].w > cut ? bd[u].w + w3 : kNegInf);
      }
      if (write_mask) *(float4*)&maskws[(size_t)i*kN + j0] = m;
      msum[ib+u] += (m.x + m.y) + (m.z + m.w);
      msq[ib+u]  += fmaf(m.x, m.x, fmaf(m.y, m.y, fmaf(m.z, m.z, m.w*m.w)));
      const float4 ml = {m.x*kL2E, m.y*kL2E, m.z*kL2E, m.w*kL2E};
      #pragma unroll
      for (int h = 0; h < kH; ++h){
        const float a = ga[h*kN + i];
        float t0 = a + bv[h].x, t1 = a + bv[h].y;
        float t2 = a + bv[h].z, t3 = a + bv[h].w;
        t0 = fmaxf(t0, 0.2f*t0); t1 = fmaxf(t1, 0.2f*t1);
        t2 = fmaxf(t2, 0.2f*t2); t3 = fmaxf(t3, 0.2f*t3);
        sv[h][0] += exp2f(fmaf(t0, kL2E, ml.x));
        sv[h][1] += exp2f(fmaf(t1, kL2E, ml.y));
        sv[h][2] += exp2f(fmaf(t2, kL2E, ml.z));
        sv[h][3] += exp2f(fmaf(t3, kL2E, ml.w));
      }
    }
  }
  // S partials: coalesced stores, no atomics
  #pragma unroll
  for (int h = 0; h < kH; ++h)
    *(float4*)&Spart[(size_t)(blockIdx.y*kH + h)*kN + j0] = *(float4*)&sv[h];

  // batched stat reductions (independent shuffle chains -> ILP)
  #pragma unroll
  for (int r = 0; r < RS; ++r){
    const float s1 = wave_sum(msum[r]);
    const float s2 = wave_sum(msq[r]);
    if (lane == 0){
      atomicAdd(&statg[2*(i0+r)+0], s1);
      atomicAdd(&statg[2*(i0+r)+1], s2);
    }
  }
}

// ---------------------------------------------------------------------------
// K2b: reduce S partials. Was 256 blocks = 1/CU (12% occupancy, latency-
// bound). Now grid (256, 8) = 2048 blocks; each block sums strips/8 strips
// for 64 consecutive outputs (coalesced 256B lines), atomicAdd into
// pre-zeroed S (8 atomics per output).
// ---------------------------------------------------------------------------
__global__ __launch_bounds__(256) void k_sred(
    const float* __restrict__ Spart, float* __restrict__ S, int strips)
{
  __shared__ float red[4][64];
  const int hj0  = blockIdx.x * 64;
  const int lane = threadIdx.x & 63;
  const int g    = threadIdx.x >> 6;
  const int per_chunk = strips >> 3;       // 64 (strips=512) or 32 (256)
  const int per_wave  = per_chunk >> 2;    // 16 or 8
  const int p0 = blockIdx.y*per_chunk + g*per_wave;
  float s0=0.f, s1=0.f, s2=0.f, s3=0.f;
  for (int p = p0; p < p0 + per_wave; p += 4){
    s0 += Spart[(size_t)(p+0)*kH*kN + hj0 + lane];
    s1 += Spart[(size_t)(p+1)*kH*kN + hj0 + lane];
    s2 += Spart[(size_t)(p+2)*kH*kN + hj0 + lane];
    s3 += Spart[(size_t)(p+3)*kH*kN + hj0 + lane];
  }
  red[g][lane] = (s0+s1)+(s2+s3);
  __syncthreads();
  if (threadIdx.x < 64)
    atomicAdd(&S[hj0+lane],
              (red[0][lane]+red[1][lane])+(red[2][lane]+red[3][lane]));
}

// ---------------------------------------------------------------------------
// K2c: finalize LN stats: statg2[i] = (mu, rsqrt(var+eps))
// ---------------------------------------------------------------------------
__global__ __launch_bounds__(256) void k_stat(
    const float* __restrict__ statg, float* __restrict__ statg2)
{
  const int i = blockIdx.x * 256 + threadIdx.x;
  const float mu  = statg[2*i] * (1.f/kN);
  const float var = statg[2*i+1] * (1.f/kN) - mu*mu;
  statg2[2*i+0] = mu;
  statg2[2*i+1] = rsqrtf(var + kLnEps);
}

// ---------------------------------------------------------------------------
// K2d: pack pS = proj/S into bf16 MFMA B-fragment layout.
// pSpack[h][kb][nt][lane][r] = bf16(pS[h][ kb*32+(lane>>4)*8+r ][ nt*16+(lane&15) ])
// ---------------------------------------------------------------------------
__global__ __launch_bounds__(256) void k_pack(
    const float* __restrict__ proj, const float* __restrict__ S,
    unsigned short* __restrict__ pSpack)
{
  const int t = blockIdx.x * 256 + threadIdx.x;   // 131072 total
  const int L  = t & 63;
  const int nt = (t >> 6) & 3;
  const int kb = (t >> 8) & 127;
  const int h  = t >> 15;
  const int f  = nt*16 + (L & 15);
  const int jb = kb*32 + (L >> 4)*8;
  union { unsigned short s[8]; uint4 v; } u;
  #pragma unroll
  for (int r = 0; r < 8; ++r){
    const int j = jb + r;
    u.s[r] = f2bf(proj[(size_t)(h*kN + j)*kFO + f] / S[h*kN + j]);
  }
  ((uint4*)pSpack)[t] = u.v;
}

// ---------------------------------------------------------------------------
// K3: aggregation via MFMA. grid (kN/16 row-groups, NQ j-slices) x 256 thr.
// Per 64-col chunk: phase A computes exps into LDS + mask_ln inline; phase B
// 4 waves = 4 heads, 2 K-steps x 4 n-tiles of mfma_f32_16x16x32_bf16.
// NEW: chunk c+1's maskws/gb loads are issued BEFORE the barrier so their
// HBM latency hides under phase B's MFMAs (async-split / T14).
// ---------------------------------------------------------------------------
__global__ __launch_bounds__(256) void k_aggr(
    const float* __restrict__ degm, const float* __restrict__ bondm,
    const float* __restrict__ maskws, int have_mask,
    const float* __restrict__ ga, const float* __restrict__ gb,
    const int* __restrict__ cutp,
    const unsigned short* __restrict__ pSpack,
    const float* __restrict__ statg2,
    float* __restrict__ accpart, float* __restrict__ mlnp)
{
  __shared__ unsigned short ebuf[kH*16*70];   // 8.96 KB
  const int tid = threadIdx.x;
  const int w   = tid >> 6;          // phase-B head
  const int L   = tid & 63;
  const int r0  = blockIdx.x * 16;
  const int jq  = blockIdx.y;
  const int span = kN / gridDim.y;
  const int nc   = span >> 6;
  const int jq0 = jq * span;
  const int ia  = tid >> 4;          // phase-A row 0..15
  const int jc  = tid & 15;          // phase-A col-quad
  const float cut = (float)cutp[0];

  float av[kH];
  #pragma unroll
  for (int hh = 0; hh < kH; ++hh) av[hh] = ga[hh*kN + r0 + ia];
  const float mu = statg2[2*(r0+ia)+0];
  const float rs = statg2[2*(r0+ia)+1];

  f32x4 acc[4];
  #pragma unroll
  for (int nt = 0; nt < 4; ++nt) acc[nt] = (f32x4){0.f,0.f,0.f,0.f};

  float4 m_n; float4 bv_n[kH];
  auto LOADC = [&](int c){
    const int jg = jq0 + c*64 + 4*jc;
    const size_t off = (size_t)(r0+ia)*kN + jg;
    if (have_mask){
      m_n = *(const float4*)&maskws[off];
    } else {
      const float4 dg = *(const float4*)&degm[off];
      const float4 bd = *(const float4*)&bondm[off];
      float w0 = dg.x + bd.x, w1 = dg.y + bd.y;
      float w2 = dg.z + bd.z, w3 = dg.w + bd.w;
      m_n.x = w0 > 0.f ? w0 : (bd.x > cut ? bd.x + w0 : kNegInf);
      m_n.y = w1 > 0.f ? w1 : (bd.y > cut ? bd.y + w1 : kNegInf);
      m_n.z = w2 > 0.f ? w2 : (bd.z > cut ? bd.z + w2 : kNegInf);
      m_n.w = w3 > 0.f ? w3 : (bd.w > cut ? bd.w + w3 : kNegInf);
    }
    #pragma unroll
    for (int hh = 0; hh < kH; ++hh)
      bv_n[hh] = *(const float4*)&gb[hh*kN + jg];
  };

  LOADC(0);
  for (int c = 0; c < nc; ++c){
    // ---- phase A (consume prefetched m/bv) ----
    {
      const float4 m = m_n;
      float4 bvl[kH];
      #pragma unroll
      for (int hh = 0; hh < kH; ++hh) bvl[hh] = bv_n[hh];

      const int jg = jq0 + c*64 + 4*jc;
      const size_t off = (size_t)(r0+ia)*kN + jg;
      float4 o;
      o.x = (m.x - mu) * rs;  o.y = (m.y - mu) * rs;
      o.z = (m.z - mu) * rs;  o.w = (m.w - mu) * rs;
      *(float4*)&mlnp[off] = o;
      const float4 ml = {m.x*kL2E, m.y*kL2E, m.z*kL2E, m.w*kL2E};
      #pragma unroll
      for (int hh = 0; hh < kH; ++hh){
        float t0 = av[hh] + bvl[hh].x, t1 = av[hh] + bvl[hh].y;
        float t2 = av[hh] + bvl[hh].z, t3 = av[hh] + bvl[hh].w;
        t0 = fmaxf(t0, 0.2f*t0); t1 = fmaxf(t1, 0.2f*t1);
        t2 = fmaxf(t2, 0.2f*t2); t3 = fmaxf(t3, 0.2f*t3);
        const float e0 = exp2f(fmaf(t0, kL2E, ml.x));
        const float e1 = exp2f(fmaf(t1, kL2E, ml.y));
        const float e2 = exp2f(fmaf(t2, kL2E, ml.z));
        const float e3 = exp2f(fmaf(t3, kL2E, ml.w));
        uint2 u;
        u.x = f2bf_pk(e0, e1);
        u.y = f2bf_pk(e2, e3);
        *(uint2*)&ebuf[(hh*16 + ia)*70 + 4*jc] = u;
      }
      if (c+1 < nc) LOADC(c+1);   // issue next chunk's loads pre-barrier
    }
    __syncthreads();
    // ---- phase B ----
    {
      const int jb = jq0 + c*64;
      const int kb0 = (jb >> 5);
      #pragma unroll
      for (int ks = 0; ks < 2; ++ks){
        const bf16x8 a = *(const bf16x8*)&ebuf[(w*16 + (L & 15))*70 + ks*32 + (L >> 4)*8];
        const int kb = kb0 + ks;
        #pragma unroll
        for (int nt = 0; nt < 4; ++nt){
          const bf16x8 b = *(const bf16x8*)&pSpack[(size_t)(((w*128 + kb)*4 + nt)*64 + L)*8];
          acc[nt] = __builtin_amdgcn_mfma_f32_16x16x32_bf16(a, b, acc[nt], 0, 0, 0);
        }
      }
    }
    __syncthreads();
  }

  // epilogue: C/D layout col=lane&15, row=(lane>>4)*4+reg -> partial store
  #pragma unroll
  for (int nt = 0; nt < 4; ++nt){
    #pragma unroll
    for (int reg = 0; reg < 4; ++reg){
      const int i = r0 + (L >> 4)*4 + reg;
      const int f = w*64 + nt*16 + (L & 15);
      accpart[((size_t)jq*kN + i)*kHF + f] = acc[nt][reg];
    }
  }
}

// ---------------------------------------------------------------------------
// K4: out = elu(sum_q accpart[q] + skip)
// ---------------------------------------------------------------------------
__global__ __launch_bounds__(256) void k_out(
    const float* __restrict__ accpart, const float* __restrict__ skipo,
    float* __restrict__ outp, int nq)
{
  const int idx = blockIdx.x * 256 + threadIdx.x;
  float o = skipo[idx];
  for (int q = 0; q < nq; ++q) o += accpart[(size_t)q*kN*kHF + idx];
  o = o > 0.f ? o : expm1f(o);
  outp[idx] = o;
}

// ---------------------------------------------------------------------------
extern "C" void kernel_launch(void* const* d_in, const int* in_sizes, int n_in,
                              void* d_out, int out_size, void* d_ws, size_t ws_size,
                              hipStream_t stream)
{
  const float* nodes = (const float*)d_in[0];
  const float* degm  = (const float*)d_in[1];
  const float* bondm = (const float*)d_in[3];
  const float* pp    = (const float*)d_in[4];
  const float* ssrc  = (const float*)d_in[5];
  const float* stgt  = (const float*)d_in[6];
  const float* skw   = (const float*)d_in[7];
  const int*   cutp  = (const int*)d_in[8];

  // ---- geometry selection based on workspace budget ----
  const size_t fixed_floats = (size_t)kH*kN*kFO + 3*(size_t)kH*kN
                            + (size_t)kN*kHF + 4*(size_t)kN + (size_t)kFI*kHF;
  const size_t psp_floats = ((size_t)kH*kN*kFO)/2;   // bf16 pack as float count
  const size_t region8 = (size_t)8*kN*kHF;           // == 512*kH*kN (Spart alias)
  const size_t region4 = (size_t)4*kN*kHF;           // == 256*kH*kN (Spart alias)
  const size_t need8      = (fixed_floats + region8 + psp_floats) * sizeof(float);
  const size_t need8_mask = need8 + (size_t)kN*kN*sizeof(float);
  const size_t need4_mask = (fixed_floats + region4 + psp_floats + (size_t)kN*kN)
                            * sizeof(float);

  int nq, strips, have_mask;
  if (ws_size >= need8_mask)      { nq = 8; strips = 512; have_mask = 1; }
  else if (ws_size >= need8)      { nq = 8; strips = 512; have_mask = 0; }
  else                            { nq = 4; strips = 256;
                                    have_mask = (ws_size >= need4_mask) ? 1 : 0; }

  float* ws     = (float*)d_ws;
  float* proj   = ws;                               // 1,048,576
  float* ga     = proj + (size_t)kH*kN*kFO;         // 16384
  float* gb     = ga + kH*kN;                       // 16384
  float* statg  = gb + kH*kN;                       // 8192
  float* statg2 = statg + 2*kN;                     // 8192
  float* S      = statg2 + 2*kN;                    // 16384 (zeroed: k_sred atomics)
  float* skip   = S + kH*kN;                        // 1,048,576
  float* skwT   = skip + (size_t)kN*kHF;            // 32768
  float* accpart= skwT + (size_t)kFI*kHF;           // nq x N x HF
  float* Spart  = accpart;                          // alias: dead before k_aggr
  unsigned short* pSpack = (unsigned short*)(accpart + (size_t)nq*kN*kHF);
  float* mask   = (float*)(pSpack + (size_t)kH*kN*kFO);

  float* outp = (float*)d_out;
  float* mlnp = outp + (size_t)kN*kHF;

  // zero statg (atomic LN stats) + statg2 (harmless) + S (atomic col-sums)
  hipMemsetAsync(statg, 0, (4*(size_t)kN + (size_t)kH*kN)*sizeof(float), stream);

  k_tr<<<kFI, 256, 0, stream>>>(skw, skwT);
  k_proj<<<kN/8, 256, 0, stream>>>(nodes, pp, ssrc, stgt, skwT, proj, ga, gb, skip);
  if (strips == 512)
    k_colsum<8><<<dim3(kN/1024, 512), 256, 0, stream>>>(degm, bondm, ga, gb, cutp,
                                                        Spart, statg, mask, have_mask);
  else
    k_colsum<16><<<dim3(kN/1024, 256), 256, 0, stream>>>(degm, bondm, ga, gb, cutp,
                                                         Spart, statg, mask, have_mask);
  k_sred<<<dim3((kH*kN)/64, 8), 256, 0, stream>>>(Spart, S, strips);
  k_stat<<<kN/256, 256, 0, stream>>>(statg, statg2);
  k_pack<<<(kH*128*4*64)/256, 256, 0, stream>>>(proj, S, pSpack);
  k_aggr<<<dim3(kN/16, nq), 256, 0, stream>>>(degm, bondm, mask, have_mask,
                                              ga, gb, cutp, pSpack, statg2,
                                              accpart, mlnp);
  k_out<<<(kN*kHF)/256, 256, 0, stream>>>(accpart, skip, outp, nq);
}

// Round 3
// 325.263 us; speedup vs baseline: 1.5620x; 1.5620x over previous
//
#include <hip/hip_runtime.h>
#include <math.h>

constexpr int kN  = 4096;
constexpr int kFI = 128;
constexpr int kFO = 64;
constexpr int kH  = 4;
constexpr int kHF = 256;   // kH*kFO
constexpr float kNegInf = -1e9f;
constexpr float kLnEps  = 1e-5f;
constexpr float kL2E    = 1.44269504f;

typedef short bf16x8 __attribute__((ext_vector_type(8)));
typedef float f32x4  __attribute__((ext_vector_type(4)));

__device__ __forceinline__ float lrelu(float x){ return x >= 0.f ? x : 0.2f*x; }

__device__ __forceinline__ float wave_sum(float v){
  #pragma unroll
  for (int s = 32; s > 0; s >>= 1) v += __shfl_xor(v, s, 64);
  return v;
}

__device__ __forceinline__ unsigned short f2bf(float x){
  unsigned u = __float_as_uint(x);
  u = (u + 0x7fffu + ((u >> 16) & 1u)) >> 16;
  return (unsigned short)u;
}
__device__ __forceinline__ unsigned f2bf_pk(float a, float b){
  return (unsigned)f2bf(a) | ((unsigned)f2bf(b) << 16);
}

// ---------------------------------------------------------------------------
// K0: transpose skw [256][128] -> skwT [128][256] so k_proj reads coalesce.
// ---------------------------------------------------------------------------
__global__ __launch_bounds__(256) void k_tr(
    const float* __restrict__ skw, float* __restrict__ skwT)
{
  const int k  = blockIdx.x;      // 0..127
  const int hf = threadIdx.x;     // 0..255
  skwT[k*kHF + hf] = skw[hf*kFI + k];
}

// ---------------------------------------------------------------------------
// K1: proj[h][n][o], ga/gb scores, skip = nodes @ skw^T. 8 nodes/block,
// 512 blocks. R2 post-mortem: the lambda/pointer prefetch variant spilled
// (VGPR=256, 351MB scratch writes, 212us). REVERTED to the plain R0 loop --
// arrays only ever indexed by unroll constants, no pointer indirection.
// ---------------------------------------------------------------------------
__global__ __launch_bounds__(256) void k_proj(
    const float* __restrict__ nodes, const float* __restrict__ pp,
    const float* __restrict__ ssrc,  const float* __restrict__ stgt,
    const float* __restrict__ skwT,
    float* __restrict__ proj, float* __restrict__ ga, float* __restrict__ gb,
    float* __restrict__ skipo)
{
  __shared__ float feat[8][kFI];    // 4 KB
  const int tid = threadIdx.x;
  const int n0  = blockIdx.x * 8;
  for (int idx = tid; idx < 8*kFI; idx += 256)
    feat[idx >> 7][idx & 127] = nodes[n0*kFI + idx];
  __syncthreads();
  const int h = tid >> 6, o = tid & 63;
  float accP[8], accS[8];
  #pragma unroll
  for (int n = 0; n < 8; ++n){ accP[n] = 0.f; accS[n] = 0.f; }
  for (int k0 = 0; k0 < kFI; k0 += 4){
    float p[4], w[4];
    #pragma unroll
    for (int u = 0; u < 4; ++u){
      p[u] = pp[(h*kFI + k0+u)*kFO + o];
      w[u] = skwT[(k0+u)*kHF + tid];
    }
    #pragma unroll
    for (int n = 0; n < 8; ++n){
      const float4 f4 = *(const float4*)&feat[n][k0];
      accP[n] = fmaf(f4.x, p[0], fmaf(f4.y, p[1],
                fmaf(f4.z, p[2], fmaf(f4.w, p[3], accP[n]))));
      accS[n] = fmaf(f4.x, w[0], fmaf(f4.y, w[1],
                fmaf(f4.z, w[2], fmaf(f4.w, w[3], accS[n]))));
    }
  }
  const float sa = ssrc[h*kFO + o];
  const float sb = stgt[h*kFO + o];
  #pragma unroll
  for (int n = 0; n < 8; ++n){
    proj[(h*kN + n0+n)*kFO + o] = accP[n];
    skipo[(n0+n)*kHF + tid]     = accS[n];
    const float va = wave_sum(accP[n] * sa);
    const float vb = wave_sum(accP[n] * sb);
    if (o == 0){ ga[h*kN + n0+n] = va; gb[h*kN + n0+n] = vb; }
  }
}

// ---------------------------------------------------------------------------
// K2: column pass + row LN stat partials. Per-wave MLP version: all 16
// float4 loads of an 8-row group issued up-front; exp2f + shared m*log2e.
// No min-wave launch bound (R1 showed occupancy is not the limiter; forcing
// it to 40 VGPR killed per-wave MLP).
// ---------------------------------------------------------------------------
template<int RS>
__global__ __launch_bounds__(256) void k_colsum(
    const float* __restrict__ degm, const float* __restrict__ bondm,
    const float* __restrict__ ga,   const float* __restrict__ gb,
    const int* __restrict__ cutp,
    float* __restrict__ Spart, float* __restrict__ statg,
    float* __restrict__ maskws, int write_mask)
{
  const int j0 = (blockIdx.x * 256 + threadIdx.x) * 4;
  const int lane = threadIdx.x & 63;
  const float cut = (float)cutp[0];
  float4 bv[kH]; f32x4 sv[kH];
  #pragma unroll
  for (int h = 0; h < kH; ++h){
    bv[h] = *(const float4*)&gb[h*kN + j0];
    sv[h] = (f32x4){0.f, 0.f, 0.f, 0.f};
  }
  float msum[RS], msq[RS];
  #pragma unroll
  for (int r = 0; r < RS; ++r){ msum[r] = 0.f; msq[r] = 0.f; }

  const int i0 = blockIdx.y * RS;
  #pragma unroll
  for (int ib = 0; ib < RS; ib += 8){
    // all 16 loads of the 8-row group in flight before any consumption
    float4 dg[8], bd[8];
    #pragma unroll
    for (int u = 0; u < 8; ++u){
      const size_t off = (size_t)(i0+ib+u)*kN + j0;
      dg[u] = *(const float4*)&degm[off];
      bd[u] = *(const float4*)&bondm[off];
    }
    #pragma unroll
    for (int u = 0; u < 8; ++u){
      const int i = i0 + ib + u;
      float4 m;
      {
        float w0 = dg[u].x + bd[u].x, w1 = dg[u].y + bd[u].y;
        float w2 = dg[u].z + bd[u].z, w3 = dg[u].w + bd[u].w;
        m.x = w0 > 0.f ? w0 : (bd[u].x > cut ? bd[u].x + w0 : kNegInf);
        m.y = w1 > 0.f ? w1 : (bd[u].y > cut ? bd[u].y + w1 : kNegInf);
        m.z = w2 > 0.f ? w2 : (bd[u].z > cut ? bd[u].z + w2 : kNegInf);
        m.w = w3 > 0.f ? w3 : (bd[u].w > cut ? bd[u].w + w3 : kNegInf);
      }
      if (write_mask) *(float4*)&maskws[(size_t)i*kN + j0] = m;
      msum[ib+u] += (m.x + m.y) + (m.z + m.w);
      msq[ib+u]  += fmaf(m.x, m.x, fmaf(m.y, m.y, fmaf(m.z, m.z, m.w*m.w)));
      const float4 ml = {m.x*kL2E, m.y*kL2E, m.z*kL2E, m.w*kL2E};
      #pragma unroll
      for (int h = 0; h < kH; ++h){
        const float a = ga[h*kN + i];
        float t0 = a + bv[h].x, t1 = a + bv[h].y;
        float t2 = a + bv[h].z, t3 = a + bv[h].w;
        t0 = fmaxf(t0, 0.2f*t0); t1 = fmaxf(t1, 0.2f*t1);
        t2 = fmaxf(t2, 0.2f*t2); t3 = fmaxf(t3, 0.2f*t3);
        sv[h][0] += exp2f(fmaf(t0, kL2E, ml.x));
        sv[h][1] += exp2f(fmaf(t1, kL2E, ml.y));
        sv[h][2] += exp2f(fmaf(t2, kL2E, ml.z));
        sv[h][3] += exp2f(fmaf(t3, kL2E, ml.w));
      }
    }
  }
  // S partials: coalesced stores, no atomics
  #pragma unroll
  for (int h = 0; h < kH; ++h)
    *(float4*)&Spart[(size_t)(blockIdx.y*kH + h)*kN + j0] = *(float4*)&sv[h];

  // batched stat reductions (independent shuffle chains -> ILP)
  #pragma unroll
  for (int r = 0; r < RS; ++r){
    const float s1 = wave_sum(msum[r]);
    const float s2 = wave_sum(msq[r]);
    if (lane == 0){
      atomicAdd(&statg[2*(i0+r)+0], s1);
      atomicAdd(&statg[2*(i0+r)+1], s2);
    }
  }
}

// ---------------------------------------------------------------------------
// K2b: reduce S partials. grid (256, 8) = 2048 blocks; each block sums
// strips/8 strips for 64 consecutive outputs, atomicAdd into pre-zeroed S.
// ---------------------------------------------------------------------------
__global__ __launch_bounds__(256) void k_sred(
    const float* __restrict__ Spart, float* __restrict__ S, int strips)
{
  __shared__ float red[4][64];
  const int hj0  = blockIdx.x * 64;
  const int lane = threadIdx.x & 63;
  const int g    = threadIdx.x >> 6;
  const int per_chunk = strips >> 3;       // 64 (strips=512) or 32 (256)
  const int per_wave  = per_chunk >> 2;    // 16 or 8
  const int p0 = blockIdx.y*per_chunk + g*per_wave;
  float s0=0.f, s1=0.f, s2=0.f, s3=0.f;
  for (int p = p0; p < p0 + per_wave; p += 4){
    s0 += Spart[(size_t)(p+0)*kH*kN + hj0 + lane];
    s1 += Spart[(size_t)(p+1)*kH*kN + hj0 + lane];
    s2 += Spart[(size_t)(p+2)*kH*kN + hj0 + lane];
    s3 += Spart[(size_t)(p+3)*kH*kN + hj0 + lane];
  }
  red[g][lane] = (s0+s1)+(s2+s3);
  __syncthreads();
  if (threadIdx.x < 64)
    atomicAdd(&S[hj0+lane],
              (red[0][lane]+red[1][lane])+(red[2][lane]+red[3][lane]));
}

// ---------------------------------------------------------------------------
// K2c: finalize LN stats: statg2[i] = (mu, rsqrt(var+eps))
// ---------------------------------------------------------------------------
__global__ __launch_bounds__(256) void k_stat(
    const float* __restrict__ statg, float* __restrict__ statg2)
{
  const int i = blockIdx.x * 256 + threadIdx.x;
  const float mu  = statg[2*i] * (1.f/kN);
  const float var = statg[2*i+1] * (1.f/kN) - mu*mu;
  statg2[2*i+0] = mu;
  statg2[2*i+1] = rsqrtf(var + kLnEps);
}

// ---------------------------------------------------------------------------
// K2d: pack pS = proj/S into bf16 MFMA B-fragment layout.
// pSpack[h][kb][nt][lane][r] = bf16(pS[h][ kb*32+(lane>>4)*8+r ][ nt*16+(lane&15) ])
// ---------------------------------------------------------------------------
__global__ __launch_bounds__(256) void k_pack(
    const float* __restrict__ proj, const float* __restrict__ S,
    unsigned short* __restrict__ pSpack)
{
  const int t = blockIdx.x * 256 + threadIdx.x;   // 131072 total
  const int L  = t & 63;
  const int nt = (t >> 6) & 3;
  const int kb = (t >> 8) & 127;
  const int h  = t >> 15;
  const int f  = nt*16 + (L & 15);
  const int jb = kb*32 + (L >> 4)*8;
  union { unsigned short s[8]; uint4 v; } u;
  #pragma unroll
  for (int r = 0; r < 8; ++r){
    const int j = jb + r;
    u.s[r] = f2bf(proj[(size_t)(h*kN + j)*kFO + f] / S[h*kN + j]);
  }
  ((uint4*)pSpack)[t] = u.v;
}

// ---------------------------------------------------------------------------
// K3: aggregation via MFMA. grid (kN/16 row-groups, NQ j-slices) x 256 thr.
// Per 64-col chunk: phase A computes exps into LDS + mask_ln inline; phase B
// 4 waves = 4 heads, 2 K-steps x 4 n-tiles of mfma_f32_16x16x32_bf16.
// Chunk c+1's maskws/gb loads issued BEFORE the barrier so their HBM
// latency hides under phase B's MFMAs (async-split / T14).
// ---------------------------------------------------------------------------
__global__ __launch_bounds__(256) void k_aggr(
    const float* __restrict__ degm, const float* __restrict__ bondm,
    const float* __restrict__ maskws, int have_mask,
    const float* __restrict__ ga, const float* __restrict__ gb,
    const int* __restrict__ cutp,
    const unsigned short* __restrict__ pSpack,
    const float* __restrict__ statg2,
    float* __restrict__ accpart, float* __restrict__ mlnp)
{
  __shared__ unsigned short ebuf[kH*16*70];   // 8.96 KB
  const int tid = threadIdx.x;
  const int w   = tid >> 6;          // phase-B head
  const int L   = tid & 63;
  const int r0  = blockIdx.x * 16;
  const int jq  = blockIdx.y;
  const int span = kN / gridDim.y;
  const int nc   = span >> 6;
  const int jq0 = jq * span;
  const int ia  = tid >> 4;          // phase-A row 0..15
  const int jc  = tid & 15;          // phase-A col-quad
  const float cut = (float)cutp[0];

  float av[kH];
  #pragma unroll
  for (int hh = 0; hh < kH; ++hh) av[hh] = ga[hh*kN + r0 + ia];
  const float mu = statg2[2*(r0+ia)+0];
  const float rs = statg2[2*(r0+ia)+1];

  f32x4 acc[4];
  #pragma unroll
  for (int nt = 0; nt < 4; ++nt) acc[nt] = (f32x4){0.f,0.f,0.f,0.f};

  float4 m_n; float4 bv_n[kH];
  auto LOADC = [&](int c){
    const int jg = jq0 + c*64 + 4*jc;
    const size_t off = (size_t)(r0+ia)*kN + jg;
    if (have_mask){
      m_n = *(const float4*)&maskws[off];
    } else {
      const float4 dg = *(const float4*)&degm[off];
      const float4 bd = *(const float4*)&bondm[off];
      float w0 = dg.x + bd.x, w1 = dg.y + bd.y;
      float w2 = dg.z + bd.z, w3 = dg.w + bd.w;
      m_n.x = w0 > 0.f ? w0 : (bd.x > cut ? bd.x + w0 : kNegInf);
      m_n.y = w1 > 0.f ? w1 : (bd.y > cut ? bd.y + w1 : kNegInf);
      m_n.z = w2 > 0.f ? w2 : (bd.z > cut ? bd.z + w2 : kNegInf);
      m_n.w = w3 > 0.f ? w3 : (bd.w > cut ? bd.w + w3 : kNegInf);
    }
    #pragma unroll
    for (int hh = 0; hh < kH; ++hh)
      bv_n[hh] = *(const float4*)&gb[hh*kN + jg];
  };

  LOADC(0);
  for (int c = 0; c < nc; ++c){
    // ---- phase A (consume prefetched m/bv) ----
    {
      const float4 m = m_n;
      float4 bvl[kH];
      #pragma unroll
      for (int hh = 0; hh < kH; ++hh) bvl[hh] = bv_n[hh];

      const int jg = jq0 + c*64 + 4*jc;
      const size_t off = (size_t)(r0+ia)*kN + jg;
      float4 o;
      o.x = (m.x - mu) * rs;  o.y = (m.y - mu) * rs;
      o.z = (m.z - mu) * rs;  o.w = (m.w - mu) * rs;
      *(float4*)&mlnp[off] = o;
      const float4 ml = {m.x*kL2E, m.y*kL2E, m.z*kL2E, m.w*kL2E};
      #pragma unroll
      for (int hh = 0; hh < kH; ++hh){
        float t0 = av[hh] + bvl[hh].x, t1 = av[hh] + bvl[hh].y;
        float t2 = av[hh] + bvl[hh].z, t3 = av[hh] + bvl[hh].w;
        t0 = fmaxf(t0, 0.2f*t0); t1 = fmaxf(t1, 0.2f*t1);
        t2 = fmaxf(t2, 0.2f*t2); t3 = fmaxf(t3, 0.2f*t3);
        const float e0 = exp2f(fmaf(t0, kL2E, ml.x));
        const float e1 = exp2f(fmaf(t1, kL2E, ml.y));
        const float e2 = exp2f(fmaf(t2, kL2E, ml.z));
        const float e3 = exp2f(fmaf(t3, kL2E, ml.w));
        uint2 u;
        u.x = f2bf_pk(e0, e1);
        u.y = f2bf_pk(e2, e3);
        *(uint2*)&ebuf[(hh*16 + ia)*70 + 4*jc] = u;
      }
      if (c+1 < nc) LOADC(c+1);   // issue next chunk's loads pre-barrier
    }
    __syncthreads();
    // ---- phase B ----
    {
      const int jb = jq0 + c*64;
      const int kb0 = (jb >> 5);
      #pragma unroll
      for (int ks = 0; ks < 2; ++ks){
        const bf16x8 a = *(const bf16x8*)&ebuf[(w*16 + (L & 15))*70 + ks*32 + (L >> 4)*8];
        const int kb = kb0 + ks;
        #pragma unroll
        for (int nt = 0; nt < 4; ++nt){
          const bf16x8 b = *(const bf16x8*)&pSpack[(size_t)(((w*128 + kb)*4 + nt)*64 + L)*8];
          acc[nt] = __builtin_amdgcn_mfma_f32_16x16x32_bf16(a, b, acc[nt], 0, 0, 0);
        }
      }
    }
    __syncthreads();
  }

  // epilogue: C/D layout col=lane&15, row=(lane>>4)*4+reg -> partial store
  #pragma unroll
  for (int nt = 0; nt < 4; ++nt){
    #pragma unroll
    for (int reg = 0; reg < 4; ++reg){
      const int i = r0 + (L >> 4)*4 + reg;
      const int f = w*64 + nt*16 + (L & 15);
      accpart[((size_t)jq*kN + i)*kHF + f] = acc[nt][reg];
    }
  }
}

// ---------------------------------------------------------------------------
// K4: out = elu(sum_q accpart[q] + skip)
// ---------------------------------------------------------------------------
__global__ __launch_bounds__(256) void k_out(
    const float* __restrict__ accpart, const float* __restrict__ skipo,
    float* __restrict__ outp, int nq)
{
  const int idx = blockIdx.x * 256 + threadIdx.x;
  float o = skipo[idx];
  for (int q = 0; q < nq; ++q) o += accpart[(size_t)q*kN*kHF + idx];
  o = o > 0.f ? o : expm1f(o);
  outp[idx] = o;
}

// ---------------------------------------------------------------------------
extern "C" void kernel_launch(void* const* d_in, const int* in_sizes, int n_in,
                              void* d_out, int out_size, void* d_ws, size_t ws_size,
                              hipStream_t stream)
{
  const float* nodes = (const float*)d_in[0];
  const float* degm  = (const float*)d_in[1];
  const float* bondm = (const float*)d_in[3];
  const float* pp    = (const float*)d_in[4];
  const float* ssrc  = (const float*)d_in[5];
  const float* stgt  = (const float*)d_in[6];
  const float* skw   = (const float*)d_in[7];
  const int*   cutp  = (const int*)d_in[8];

  // ---- geometry selection based on workspace budget ----
  const size_t fixed_floats = (size_t)kH*kN*kFO + 3*(size_t)kH*kN
                            + (size_t)kN*kHF + 4*(size_t)kN + (size_t)kFI*kHF;
  const size_t psp_floats = ((size_t)kH*kN*kFO)/2;   // bf16 pack as float count
  const size_t region8 = (size_t)8*kN*kHF;           // == 512*kH*kN (Spart alias)
  const size_t region4 = (size_t)4*kN*kHF;           // == 256*kH*kN (Spart alias)
  const size_t need8      = (fixed_floats + region8 + psp_floats) * sizeof(float);
  const size_t need8_mask = need8 + (size_t)kN*kN*sizeof(float);
  const size_t need4_mask = (fixed_floats + region4 + psp_floats + (size_t)kN*kN)
                            * sizeof(float);

  int nq, strips, have_mask;
  if (ws_size >= need8_mask)      { nq = 8; strips = 512; have_mask = 1; }
  else if (ws_size >= need8)      { nq = 8; strips = 512; have_mask = 0; }
  else                            { nq = 4; strips = 256;
                                    have_mask = (ws_size >= need4_mask) ? 1 : 0; }

  float* ws     = (float*)d_ws;
  float* proj   = ws;                               // 1,048,576
  float* ga     = proj + (size_t)kH*kN*kFO;         // 16384
  float* gb     = ga + kH*kN;                       // 16384
  float* statg  = gb + kH*kN;                       // 8192
  float* statg2 = statg + 2*kN;                     // 8192
  float* S      = statg2 + 2*kN;                    // 16384 (zeroed: k_sred atomics)
  float* skip   = S + kH*kN;                        // 1,048,576
  float* skwT   = skip + (size_t)kN*kHF;            // 32768
  float* accpart= skwT + (size_t)kFI*kHF;           // nq x N x HF
  float* Spart  = accpart;                          // alias: dead before k_aggr
  unsigned short* pSpack = (unsigned short*)(accpart + (size_t)nq*kN*kHF);
  float* mask   = (float*)(pSpack + (size_t)kH*kN*kFO);

  float* outp = (float*)d_out;
  float* mlnp = outp + (size_t)kN*kHF;

  // zero statg (atomic LN stats) + statg2 (harmless) + S (atomic col-sums)
  hipMemsetAsync(statg, 0, (4*(size_t)kN + (size_t)kH*kN)*sizeof(float), stream);

  k_tr<<<kFI, 256, 0, stream>>>(skw, skwT);
  k_proj<<<kN/8, 256, 0, stream>>>(nodes, pp, ssrc, stgt, skwT, proj, ga, gb, skip);
  if (strips == 512)
    k_colsum<8><<<dim3(kN/1024, 512), 256, 0, stream>>>(degm, bondm, ga, gb, cutp,
                                                        Spart, statg, mask, have_mask);
  else
    k_colsum<16><<<dim3(kN/1024, 256), 256, 0, stream>>>(degm, bondm, ga, gb, cutp,
                                                         Spart, statg, mask, have_mask);
  k_sred<<<dim3((kH*kN)/64, 8), 256, 0, stream>>>(Spart, S, strips);
  k_stat<<<kN/256, 256, 0, stream>>>(statg, statg2);
  k_pack<<<(kH*128*4*64)/256, 256, 0, stream>>>(proj, S, pSpack);
  k_aggr<<<dim3(kN/16, nq), 256, 0, stream>>>(degm, bondm, mask, have_mask,
                                              ga, gb, cutp, pSpack, statg2,
                                              accpart, mlnp);
  k_out<<<(kN*kHF)/256, 256, 0, stream>>>(accpart, skip, outp, nq);
}